// Round 2
// baseline (1973.279 us; speedup 1.0000x reference)
//
#include <hip/hip_runtime.h>
#include <math.h>

#define BQ 8
#define NQ 2048
#define SQ 1024
#define KQ 64
#define CIN 64
#define H1Q 128
#define COUT 256
#define R2F 0.04f     /* f32(0.2**2 in double) = 0x3D23D70A; NOT 0.2f*0.2f */
#define CAP 512

// ---------------------------------------------------------------------------
// Kernel 1: farthest point sampling, one block per cloud.
// Must match jnp bit-exactly: d2 = ((dx*dx + dy*dy) + dz*dz) with no FMA
// contraction; argmax = first occurrence of max (tie -> smaller index).
// ---------------------------------------------------------------------------
__global__ __launch_bounds__(1024)
void fps_kernel(const float* __restrict__ pos, int* __restrict__ idx_out,
                float* __restrict__ q_out, float* __restrict__ batch_out) {
    __shared__ float px[NQ], py[NQ], pz[NQ], dist[NQ];
    __shared__ int   sel[SQ];
    __shared__ float wv_s[16];
    __shared__ int   wi_s[16];
    __shared__ float ccx, ccy, ccz;

    const int b = blockIdx.x, tid = threadIdx.x;
    const float* p = pos + (size_t)b * NQ * 3;
    for (int i = tid; i < NQ; i += 1024) {
        px[i] = p[3*i]; py[i] = p[3*i+1]; pz[i] = p[3*i+2];
    }
    if (tid == 0) sel[0] = 0;
    __syncthreads();

    float cx = px[0], cy = py[0], cz = pz[0];

    for (int s = 1; s < SQ; ++s) {
        // fused: update dist with center chosen at s-1, track argmax
        float bv = -1.0f; int bi = 0x7fffffff;
        for (int i = tid; i < NQ; i += 1024) {
            float dx = __fsub_rn(px[i], cx);
            float dy = __fsub_rn(py[i], cy);
            float dz = __fsub_rn(pz[i], cz);
            float nd = __fadd_rn(__fadd_rn(__fmul_rn(dx, dx), __fmul_rn(dy, dy)),
                                 __fmul_rn(dz, dz));
            float od = (s == 1) ? INFINITY : dist[i];
            float v  = fminf(od, nd);
            dist[i] = v;
            if (v > bv || (v == bv && i < bi)) { bv = v; bi = i; }
        }
        // wave (64-lane) reduce: larger value wins, tie -> smaller index
        for (int off = 32; off; off >>= 1) {
            float ov = __shfl_down(bv, off);
            int   oi = __shfl_down(bi, off);
            if (ov > bv || (ov == bv && oi < bi)) { bv = ov; bi = oi; }
        }
        if ((tid & 63) == 0) { wv_s[tid >> 6] = bv; wi_s[tid >> 6] = bi; }
        __syncthreads();
        if (tid < 64) {
            float v2 = (tid < 16) ? wv_s[tid] : -1.0f;
            int   i2 = (tid < 16) ? wi_s[tid] : 0x7fffffff;
            for (int off = 8; off; off >>= 1) {
                float ov = __shfl_down(v2, off);
                int   oi = __shfl_down(i2, off);
                if (ov > v2 || (ov == v2 && oi < i2)) { v2 = ov; i2 = oi; }
            }
            if (tid == 0) { sel[s] = i2; ccx = px[i2]; ccy = py[i2]; ccz = pz[i2]; }
        }
        __syncthreads();
        cx = ccx; cy = ccy; cz = ccz;
    }

    for (int s = tid; s < SQ; s += 1024) {
        int id = sel[s];
        idx_out[b*SQ + s] = id;
        q_out[(size_t)(b*SQ + s)*3 + 0] = px[id];
        q_out[(size_t)(b*SQ + s)*3 + 1] = py[id];
        q_out[(size_t)(b*SQ + s)*3 + 2] = pz[id];
        batch_out[b*SQ + s] = (float)b;
    }
}

// ---------------------------------------------------------------------------
// Kernel 2: radius ball query, one block per center. Selects the set of the
// K smallest d2 <= R2 (ties -> lower point index), matching lax.top_k's
// stable selection. Order of stored neighbors is irrelevant (max-agg).
// ---------------------------------------------------------------------------
__global__ __launch_bounds__(256)
void ball_kernel(const float* __restrict__ pos, const float* __restrict__ q,
                 int* __restrict__ nbr, int* __restrict__ cnt_out) {
    const int cidx = blockIdx.x;
    const int b = cidx >> 10;
    __shared__ float sd2[CAP];
    __shared__ int   sid[CAP];
    __shared__ int   s_cnt, s_w;
    if (threadIdx.x == 0) { s_cnt = 0; s_w = 0; }
    __syncthreads();

    const float qx = q[(size_t)cidx*3], qy = q[(size_t)cidx*3+1], qz = q[(size_t)cidx*3+2];
    const float* p = pos + (size_t)b * NQ * 3;
    for (int i = threadIdx.x; i < NQ; i += 256) {
        float dx = __fsub_rn(qx, p[3*i]);
        float dy = __fsub_rn(qy, p[3*i+1]);
        float dz = __fsub_rn(qz, p[3*i+2]);
        float d2 = __fadd_rn(__fadd_rn(__fmul_rn(dx, dx), __fmul_rn(dy, dy)),
                             __fmul_rn(dz, dz));
        if (d2 <= R2F) {
            int slot = atomicAdd(&s_cnt, 1);
            if (slot < CAP) { sd2[slot] = d2; sid[slot] = i; }
        }
    }
    __syncthreads();
    int cnt = min(s_cnt, CAP);
    if (cnt <= KQ) {
        for (int t = threadIdx.x; t < cnt; t += 256) nbr[(size_t)cidx*KQ + t] = sid[t];
        if (threadIdx.x == 0) cnt_out[cidx] = cnt;
    } else {
        for (int t = threadIdx.x; t < cnt; t += 256) {
            float d = sd2[t]; int id = sid[t];
            int rank = 0;
            for (int u = 0; u < cnt; ++u) {
                float du = sd2[u];
                rank += (du < d || (du == d && sid[u] < id)) ? 1 : 0;
            }
            if (rank < KQ) { int w = atomicAdd(&s_w, 1); nbr[(size_t)cidx*KQ + w] = id; }
        }
        if (threadIdx.x == 0) cnt_out[cidx] = KQ;
    }
}

// ---------------------------------------------------------------------------
// Kernel 3: xw = x @ w1[:64] + b1  (per-point, hoisted out of the edge loop)
// ---------------------------------------------------------------------------
__global__ __launch_bounds__(128)
void xw_kernel(const float* __restrict__ x, const float* __restrict__ w1,
               const float* __restrict__ b1, float* __restrict__ xw) {
    __shared__ float xs[8][CIN];
    const int r0 = blockIdx.x * 8;
    const int h  = threadIdx.x;
    for (int i = h; i < 8*CIN; i += 128)
        xs[i >> 6][i & 63] = x[(size_t)(r0 + (i >> 6))*CIN + (i & 63)];
    __syncthreads();
    float bb = b1[h];
    float acc[8];
#pragma unroll
    for (int r = 0; r < 8; ++r) acc[r] = bb;
    for (int c = 0; c < CIN; ++c) {
        float wv = w1[c*H1Q + h];
#pragma unroll
        for (int r = 0; r < 8; ++r) acc[r] = fmaf(xs[r][c], wv, acc[r]);
    }
#pragma unroll
    for (int r = 0; r < 8; ++r) xw[(size_t)(r0 + r)*H1Q + h] = acc[r];
}

// ---------------------------------------------------------------------------
// Kernel 4: per-center edge MLP + masked max aggregation.
// Phase A: h1[e][h] = relu(xw[b*N+j] + (pos_j - q) @ w1[64:67]) for all cnt
//          edges into LDS (<= 64x128 f32 = 32 KB).
// Phase B: 8 groups x 32 lanes x 8 channels; group g handles edges
//          [8g, 8g+8). LDS h1 reads are same-address within a group
//          (broadcast, conflict-free) and amortized over 8 channels.
// ---------------------------------------------------------------------------
__global__ __launch_bounds__(256)
void conv_kernel(const float* __restrict__ pos, const float* __restrict__ q,
                 const int* __restrict__ nbr, const int* __restrict__ cnt_in,
                 const float* __restrict__ xw, const float* __restrict__ w1,
                 const float* __restrict__ w2, const float* __restrict__ b2,
                 float* __restrict__ out) {
    const int cidx = blockIdx.x;
    const int b = cidx >> 10;
    const int tid = threadIdx.x;
    __shared__ float hs[KQ][H1Q];           // 32 KB
    __shared__ float vs[8][COUT];           // 8 KB
    __shared__ float dxs[KQ], dys[KQ], dzs[KQ];
    __shared__ int   js[KQ];

    const int cnt = cnt_in[cidx];
    if (cnt == 0) {
        out[(size_t)cidx*COUT + tid] = 0.0f;
        return;
    }
    const float qx = q[(size_t)cidx*3], qy = q[(size_t)cidx*3+1], qz = q[(size_t)cidx*3+2];
    const float* p = pos + (size_t)b * NQ * 3;
    if (tid < cnt) {
        int j = nbr[(size_t)cidx*KQ + tid];
        js[tid]  = j;
        dxs[tid] = p[3*j]   - qx;
        dys[tid] = p[3*j+1] - qy;
        dzs[tid] = p[3*j+2] - qz;
    }
    __syncthreads();

    const float* w1p = w1 + (size_t)CIN * H1Q;   // rows 64..66
    for (int f = tid; f < cnt*H1Q; f += 256) {
        int e = f >> 7, h = f & 127;
        int j = js[e];
        // FIX (round 1 bug): xw rows are GLOBAL point rows; nbr holds
        // cloud-local indices, so offset by b*NQ. Clouds b>0 were reading
        // cloud 0's features before.
        float v = xw[((size_t)b*NQ + j)*H1Q + h];
        v = fmaf(dxs[e], w1p[h],         v);
        v = fmaf(dys[e], w1p[H1Q + h],   v);
        v = fmaf(dzs[e], w1p[2*H1Q + h], v);
        hs[e][h] = fmaxf(v, 0.0f);
    }
    __syncthreads();

    const int grp = tid >> 5;        // 0..7, edge tile
    const int c0  = (tid & 31) * 8;  // 8 contiguous channels
    const int e0  = grp * 8;
    float vmax[8];
#pragma unroll
    for (int j = 0; j < 8; ++j) vmax[j] = -INFINITY;

    const int ne = min(8, cnt - e0);
    if (ne > 0) {
        float acc[8][8];
#pragma unroll
        for (int e = 0; e < 8; ++e)
#pragma unroll
            for (int j = 0; j < 8; ++j) acc[e][j] = 0.0f;

        for (int h = 0; h < H1Q; ++h) {
            const float4 wa = *(const float4*)&w2[(size_t)h*COUT + c0];
            const float4 wb = *(const float4*)&w2[(size_t)h*COUT + c0 + 4];
#pragma unroll
            for (int e = 0; e < 8; ++e) {
                float hv = hs[e0 + e][h];
                acc[e][0] = fmaf(hv, wa.x, acc[e][0]);
                acc[e][1] = fmaf(hv, wa.y, acc[e][1]);
                acc[e][2] = fmaf(hv, wa.z, acc[e][2]);
                acc[e][3] = fmaf(hv, wa.w, acc[e][3]);
                acc[e][4] = fmaf(hv, wb.x, acc[e][4]);
                acc[e][5] = fmaf(hv, wb.y, acc[e][5]);
                acc[e][6] = fmaf(hv, wb.z, acc[e][6]);
                acc[e][7] = fmaf(hv, wb.w, acc[e][7]);
            }
        }
#pragma unroll
        for (int e = 0; e < 8; ++e) {
            if (e < ne) {
#pragma unroll
                for (int j = 0; j < 8; ++j) vmax[j] = fmaxf(vmax[j], acc[e][j]);
            }
        }
    }
#pragma unroll
    for (int j = 0; j < 8; ++j) vs[grp][c0 + j] = vmax[j];
    __syncthreads();

    // combine the 8 edge-groups; channel = tid
    float m = vs[0][tid];
#pragma unroll
    for (int g = 1; g < 8; ++g) m = fmaxf(m, vs[g][tid]);
    m += b2[tid];
    out[(size_t)cidx*COUT + tid] = m;
}

// ---------------------------------------------------------------------------
extern "C" void kernel_launch(void* const* d_in, const int* in_sizes, int n_in,
                              void* d_out, int out_size, void* d_ws, size_t ws_size,
                              hipStream_t stream) {
    const float* x   = (const float*)d_in[0];
    const float* pos = (const float*)d_in[1];
    // d_in[2] = batch (implicit, unused)
    const float* w1  = (const float*)d_in[3];
    const float* b1  = (const float*)d_in[4];
    const float* w2  = (const float*)d_in[5];
    const float* b2  = (const float*)d_in[6];

    float* out  = (float*)d_out;                         // [B*S, 256]
    float* qbuf = out + (size_t)BQ*SQ*COUT;              // [B*S, 3]
    float* bbuf = qbuf + (size_t)BQ*SQ*3;                // [B*S]

    char* ws = (char*)d_ws;
    int*   idx = (int*)(ws);                                     // 32 KB
    int*   cnt = (int*)(ws + 32768);                             // 32 KB
    int*   nbr = (int*)(ws + 65536);                             // 2 MB
    float* xw  = (float*)(ws + 65536 + (size_t)BQ*SQ*KQ*4);      // 8 MB

    fps_kernel <<<BQ,      1024, 0, stream>>>(pos, idx, qbuf, bbuf);
    ball_kernel<<<BQ*SQ,    256, 0, stream>>>(pos, qbuf, nbr, cnt);
    xw_kernel  <<<(BQ*NQ)/8, 128, 0, stream>>>(x, w1, b1, xw);
    conv_kernel<<<BQ*SQ,    256, 0, stream>>>(pos, qbuf, nbr, cnt, xw, w1, w2, b2, out);
}

// Round 3
// 1196.507 us; speedup vs baseline: 1.6492x; 1.6492x over previous
//
#include <hip/hip_runtime.h>
#include <math.h>

#define BQ 8
#define NQ 2048
#define SQ 1024
#define KQ 64
#define CIN 64
#define H1Q 128
#define COUT 256
#define R2F 0.04f     /* f32(0.2**2 in double) = 0x3D23D70A; NOT 0.2f*0.2f */
#define CAP 512

// ---------------------------------------------------------------------------
// DPP wave-max helper (gfx9/CDNA row ops). old = -inf so invalid lanes
// contribute the identity. After shr 1,2,4,8 + bcast15 + bcast31, lane 63
// holds the max of all 64 lanes.
// ---------------------------------------------------------------------------
template <int CTRL>
__device__ __forceinline__ float maxdpp(float x) {
    int xi = __builtin_bit_cast(int, x);
    int yi = __builtin_amdgcn_update_dpp((int)0xFF800000, xi, CTRL, 0xF, 0xF, false);
    return fmaxf(x, __builtin_bit_cast(float, yi));
}

// ---------------------------------------------------------------------------
// Kernel 1: farthest point sampling — ONE WAVE per cloud, points in registers
// (lane-major: lane L owns global indices L*32+r, so first-occurrence argmax
// tie-break == (lowest lane, lowest r)). No barriers in the serial loop.
// d2 must match jnp bit-exactly: ((dx*dx + dy*dy) + dz*dz), no FMA.
// ---------------------------------------------------------------------------
__global__ __launch_bounds__(64)
void fps_kernel(const float* __restrict__ pos, int* __restrict__ idx_out,
                float* __restrict__ q_out, float* __restrict__ batch_out) {
    __shared__ float lpx[NQ], lpy[NQ], lpz[NQ];
    __shared__ int   sel[SQ];

    const int b = blockIdx.x, lane = threadIdx.x;
    const float* p = pos + (size_t)b * NQ * 3;

    float px[32], py[32], pz[32], dist[32];
#pragma unroll
    for (int r = 0; r < 32; ++r) {
        int i = lane * 32 + r;
        px[r] = p[3*i]; py[r] = p[3*i+1]; pz[r] = p[3*i+2];
        lpx[i] = px[r]; lpy[i] = py[r]; lpz[i] = pz[r];
    }
    if (lane == 0) sel[0] = 0;
    __syncthreads();   // one wave: cheap; makes LDS staging visible

    float cx = __shfl(px[0], 0), cy = __shfl(py[0], 0), cz = __shfl(pz[0], 0);

    float lmax = -INFINITY;
#pragma unroll
    for (int r = 0; r < 32; ++r) {
        float dx = __fsub_rn(px[r], cx);
        float dy = __fsub_rn(py[r], cy);
        float dz = __fsub_rn(pz[r], cz);
        float nd = __fadd_rn(__fadd_rn(__fmul_rn(dx, dx), __fmul_rn(dy, dy)),
                             __fmul_rn(dz, dz));
        dist[r] = nd;
        lmax = fmaxf(lmax, nd);
    }

    for (int s = 1; s < SQ; ++s) {
        // ---- wave argmax, tie -> smallest global index ----
        float m = lmax;
        m = maxdpp<0x111>(m);   // row_shr:1
        m = maxdpp<0x112>(m);   // row_shr:2
        m = maxdpp<0x114>(m);   // row_shr:4
        m = maxdpp<0x118>(m);   // row_shr:8
        m = maxdpp<0x142>(m);   // row_bcast:15
        m = maxdpp<0x143>(m);   // row_bcast:31
        float wmax = __builtin_bit_cast(
            float, __builtin_amdgcn_readlane(__builtin_bit_cast(int, m), 63));

        unsigned long long msk = __ballot(lmax == wmax);
        int wl = __ffsll(msk) - 1;          // lowest matching lane
        int ridx = 1000;
#pragma unroll
        for (int r = 31; r >= 0; --r)       // lowest matching reg in each lane
            ridx = (dist[r] == wmax) ? r : ridx;
        int rw  = __shfl(ridx, wl);
        int gidx = wl * 32 + rw;            // global first-occurrence argmax
        if (lane == 0) sel[s] = gidx;

        // ---- broadcast new center (uniform-address LDS read) ----
        cx = lpx[gidx]; cy = lpy[gidx]; cz = lpz[gidx];

        // ---- distance update + fresh lane max ----
        lmax = -INFINITY;
#pragma unroll
        for (int r = 0; r < 32; ++r) {
            float dx = __fsub_rn(px[r], cx);
            float dy = __fsub_rn(py[r], cy);
            float dz = __fsub_rn(pz[r], cz);
            float nd = __fadd_rn(__fadd_rn(__fmul_rn(dx, dx), __fmul_rn(dy, dy)),
                                 __fmul_rn(dz, dz));
            float v  = fminf(dist[r], nd);
            dist[r] = v;
            lmax = fmaxf(lmax, v);
        }
    }
    __syncthreads();   // sel[] visible for the output pass

    for (int s = lane; s < SQ; s += 64) {
        int id = sel[s];
        idx_out[b*SQ + s] = id;
        q_out[(size_t)(b*SQ + s)*3 + 0] = lpx[id];
        q_out[(size_t)(b*SQ + s)*3 + 1] = lpy[id];
        q_out[(size_t)(b*SQ + s)*3 + 2] = lpz[id];
        batch_out[b*SQ + s] = (float)b;
    }
}

// ---------------------------------------------------------------------------
// Kernel 2: radius ball query, one block per center. Selects the set of the
// K smallest d2 <= R2 (ties -> lower point index), matching lax.top_k's
// stable selection. Order of stored neighbors is irrelevant (max-agg).
// ---------------------------------------------------------------------------
__global__ __launch_bounds__(256)
void ball_kernel(const float* __restrict__ pos, const float* __restrict__ q,
                 int* __restrict__ nbr, int* __restrict__ cnt_out) {
    const int cidx = blockIdx.x;
    const int b = cidx >> 10;
    __shared__ float sd2[CAP];
    __shared__ int   sid[CAP];
    __shared__ int   s_cnt, s_w;
    if (threadIdx.x == 0) { s_cnt = 0; s_w = 0; }
    __syncthreads();

    const float qx = q[(size_t)cidx*3], qy = q[(size_t)cidx*3+1], qz = q[(size_t)cidx*3+2];
    const float* p = pos + (size_t)b * NQ * 3;
    for (int i = threadIdx.x; i < NQ; i += 256) {
        float dx = __fsub_rn(qx, p[3*i]);
        float dy = __fsub_rn(qy, p[3*i+1]);
        float dz = __fsub_rn(qz, p[3*i+2]);
        float d2 = __fadd_rn(__fadd_rn(__fmul_rn(dx, dx), __fmul_rn(dy, dy)),
                             __fmul_rn(dz, dz));
        if (d2 <= R2F) {
            int slot = atomicAdd(&s_cnt, 1);
            if (slot < CAP) { sd2[slot] = d2; sid[slot] = i; }
        }
    }
    __syncthreads();
    int cnt = min(s_cnt, CAP);
    if (cnt <= KQ) {
        for (int t = threadIdx.x; t < cnt; t += 256) nbr[(size_t)cidx*KQ + t] = sid[t];
        if (threadIdx.x == 0) cnt_out[cidx] = cnt;
    } else {
        for (int t = threadIdx.x; t < cnt; t += 256) {
            float d = sd2[t]; int id = sid[t];
            int rank = 0;
            for (int u = 0; u < cnt; ++u) {
                float du = sd2[u];
                rank += (du < d || (du == d && sid[u] < id)) ? 1 : 0;
            }
            if (rank < KQ) { int w = atomicAdd(&s_w, 1); nbr[(size_t)cidx*KQ + w] = id; }
        }
        if (threadIdx.x == 0) cnt_out[cidx] = KQ;
    }
}

// ---------------------------------------------------------------------------
// Kernel 3: xw = x @ w1[:64] + b1  (per-point, hoisted out of the edge loop)
// ---------------------------------------------------------------------------
__global__ __launch_bounds__(128)
void xw_kernel(const float* __restrict__ x, const float* __restrict__ w1,
               const float* __restrict__ b1, float* __restrict__ xw) {
    __shared__ float xs[8][CIN];
    const int r0 = blockIdx.x * 8;
    const int h  = threadIdx.x;
    for (int i = h; i < 8*CIN; i += 128)
        xs[i >> 6][i & 63] = x[(size_t)(r0 + (i >> 6))*CIN + (i & 63)];
    __syncthreads();
    float bb = b1[h];
    float acc[8];
#pragma unroll
    for (int r = 0; r < 8; ++r) acc[r] = bb;
    for (int c = 0; c < CIN; ++c) {
        float wv = w1[c*H1Q + h];
#pragma unroll
        for (int r = 0; r < 8; ++r) acc[r] = fmaf(xs[r][c], wv, acc[r]);
    }
#pragma unroll
    for (int r = 0; r < 8; ++r) xw[(size_t)(r0 + r)*H1Q + h] = acc[r];
}

// ---------------------------------------------------------------------------
// Kernel 4: per-center edge MLP + masked max aggregation.
// ---------------------------------------------------------------------------
__global__ __launch_bounds__(256)
void conv_kernel(const float* __restrict__ pos, const float* __restrict__ q,
                 const int* __restrict__ nbr, const int* __restrict__ cnt_in,
                 const float* __restrict__ xw, const float* __restrict__ w1,
                 const float* __restrict__ w2, const float* __restrict__ b2,
                 float* __restrict__ out) {
    const int cidx = blockIdx.x;
    const int b = cidx >> 10;
    const int tid = threadIdx.x;
    __shared__ float hs[KQ][H1Q];           // 32 KB
    __shared__ float vs[8][COUT];           // 8 KB
    __shared__ float dxs[KQ], dys[KQ], dzs[KQ];
    __shared__ int   js[KQ];

    const int cnt = cnt_in[cidx];
    if (cnt == 0) {
        out[(size_t)cidx*COUT + tid] = 0.0f;
        return;
    }
    const float qx = q[(size_t)cidx*3], qy = q[(size_t)cidx*3+1], qz = q[(size_t)cidx*3+2];
    const float* p = pos + (size_t)b * NQ * 3;
    if (tid < cnt) {
        int j = nbr[(size_t)cidx*KQ + tid];
        js[tid]  = j;
        dxs[tid] = p[3*j]   - qx;
        dys[tid] = p[3*j+1] - qy;
        dzs[tid] = p[3*j+2] - qz;
    }
    __syncthreads();

    const float* w1p = w1 + (size_t)CIN * H1Q;   // rows 64..66
    for (int f = tid; f < cnt*H1Q; f += 256) {
        int e = f >> 7, h = f & 127;
        int j = js[e];
        float v = xw[((size_t)b*NQ + j)*H1Q + h];   // global point row
        v = fmaf(dxs[e], w1p[h],         v);
        v = fmaf(dys[e], w1p[H1Q + h],   v);
        v = fmaf(dzs[e], w1p[2*H1Q + h], v);
        hs[e][h] = fmaxf(v, 0.0f);
    }
    __syncthreads();

    const int grp = tid >> 5;        // 0..7, edge tile
    const int c0  = (tid & 31) * 8;  // 8 contiguous channels
    const int e0  = grp * 8;
    float vmax[8];
#pragma unroll
    for (int j = 0; j < 8; ++j) vmax[j] = -INFINITY;

    const int ne = min(8, cnt - e0);
    if (ne > 0) {
        float acc[8][8];
#pragma unroll
        for (int e = 0; e < 8; ++e)
#pragma unroll
            for (int j = 0; j < 8; ++j) acc[e][j] = 0.0f;

        for (int h = 0; h < H1Q; ++h) {
            const float4 wa = *(const float4*)&w2[(size_t)h*COUT + c0];
            const float4 wb = *(const float4*)&w2[(size_t)h*COUT + c0 + 4];
#pragma unroll
            for (int e = 0; e < 8; ++e) {
                float hv = hs[e0 + e][h];
                acc[e][0] = fmaf(hv, wa.x, acc[e][0]);
                acc[e][1] = fmaf(hv, wa.y, acc[e][1]);
                acc[e][2] = fmaf(hv, wa.z, acc[e][2]);
                acc[e][3] = fmaf(hv, wa.w, acc[e][3]);
                acc[e][4] = fmaf(hv, wb.x, acc[e][4]);
                acc[e][5] = fmaf(hv, wb.y, acc[e][5]);
                acc[e][6] = fmaf(hv, wb.z, acc[e][6]);
                acc[e][7] = fmaf(hv, wb.w, acc[e][7]);
            }
        }
#pragma unroll
        for (int e = 0; e < 8; ++e) {
            if (e < ne) {
#pragma unroll
                for (int j = 0; j < 8; ++j) vmax[j] = fmaxf(vmax[j], acc[e][j]);
            }
        }
    }
#pragma unroll
    for (int j = 0; j < 8; ++j) vs[grp][c0 + j] = vmax[j];
    __syncthreads();

    float m = vs[0][tid];
#pragma unroll
    for (int g = 1; g < 8; ++g) m = fmaxf(m, vs[g][tid]);
    m += b2[tid];
    out[(size_t)cidx*COUT + tid] = m;
}

// ---------------------------------------------------------------------------
extern "C" void kernel_launch(void* const* d_in, const int* in_sizes, int n_in,
                              void* d_out, int out_size, void* d_ws, size_t ws_size,
                              hipStream_t stream) {
    const float* x   = (const float*)d_in[0];
    const float* pos = (const float*)d_in[1];
    // d_in[2] = batch (implicit, unused)
    const float* w1  = (const float*)d_in[3];
    const float* b1  = (const float*)d_in[4];
    const float* w2  = (const float*)d_in[5];
    const float* b2  = (const float*)d_in[6];

    float* out  = (float*)d_out;                         // [B*S, 256]
    float* qbuf = out + (size_t)BQ*SQ*COUT;              // [B*S, 3]
    float* bbuf = qbuf + (size_t)BQ*SQ*3;                // [B*S]

    char* ws = (char*)d_ws;
    int*   idx = (int*)(ws);                                     // 32 KB
    int*   cnt = (int*)(ws + 32768);                             // 32 KB
    int*   nbr = (int*)(ws + 65536);                             // 2 MB
    float* xw  = (float*)(ws + 65536 + (size_t)BQ*SQ*KQ*4);      // 8 MB

    fps_kernel <<<BQ,        64, 0, stream>>>(pos, idx, qbuf, bbuf);
    ball_kernel<<<BQ*SQ,    256, 0, stream>>>(pos, qbuf, nbr, cnt);
    xw_kernel  <<<(BQ*NQ)/8, 128, 0, stream>>>(x, w1, b1, xw);
    conv_kernel<<<BQ*SQ,    256, 0, stream>>>(pos, qbuf, nbr, cnt, xw, w1, w2, b2, out);
}

// Round 4
// 1139.276 us; speedup vs baseline: 1.7320x; 1.0502x over previous
//
#include <hip/hip_runtime.h>
#include <math.h>

#define BQ 8
#define NQ 2048
#define SQ 1024
#define KQ 64
#define CIN 64
#define H1Q 128
#define COUT 256
#define R2F 0.04f     /* f32(0.2**2 in double) = 0x3D23D70A; NOT 0.2f*0.2f */
#define CAP 512

typedef float f32x2 __attribute__((ext_vector_type(2)));

// ---------------------------------------------------------------------------
// DPP wave-max helper (gfx9/CDNA row ops). old = -inf so shifted-in lanes
// contribute the identity. After shr 1,2,4,8 + bcast15 + bcast31, lane 63
// holds the max of all 64 lanes.
// ---------------------------------------------------------------------------
template <int CTRL>
__device__ __forceinline__ float maxdpp(float x) {
    int xi = __builtin_bit_cast(int, x);
    int yi = __builtin_amdgcn_update_dpp((int)0xFF800000, xi, CTRL, 0xF, 0xF, false);
    return fmaxf(x, __builtin_bit_cast(float, yi));
}

// ---------------------------------------------------------------------------
// Kernel 1: farthest point sampling — ONE WAVE per cloud, points in registers
// as float2 pairs (lane-major: lane L owns global indices [L*32, L*32+32),
// reg r holds {L*32+2r, L*32+2r+1}), so (lane, reg, elem) lexicographic ==
// global index order and first-occurrence argmax is preserved.
// d2 must match jnp bit-exactly: ((dx*dx+dy*dy)+dz*dz), no FMA, no reassoc
// (fp contract off; x+(-c) is bitwise == x-c).
// ---------------------------------------------------------------------------
__global__ __launch_bounds__(64)
void fps_kernel(const float* __restrict__ pos, int* __restrict__ idx_out,
                float* __restrict__ q_out, float* __restrict__ batch_out) {
#pragma clang fp contract(off)
    __shared__ float lpos[NQ][4];   // padded -> single ds_read_b128 center fetch
    __shared__ int   sel[SQ];

    const int b = blockIdx.x, lane = threadIdx.x;
    const float* p = pos + (size_t)b * NQ * 3;

    f32x2 px[16], py[16], pz[16], dist[16];
#pragma unroll
    for (int r = 0; r < 16; ++r) {
        int i0 = lane * 32 + 2 * r;
        float x0 = p[3*i0],   y0 = p[3*i0+1], z0 = p[3*i0+2];
        float x1 = p[3*i0+3], y1 = p[3*i0+4], z1 = p[3*i0+5];
        px[r] = (f32x2){x0, x1}; py[r] = (f32x2){y0, y1}; pz[r] = (f32x2){z0, z1};
        lpos[i0][0] = x0; lpos[i0][1] = y0; lpos[i0][2] = z0; lpos[i0][3] = 0.f;
        lpos[i0+1][0] = x1; lpos[i0+1][1] = y1; lpos[i0+1][2] = z1; lpos[i0+1][3] = 0.f;
    }
    if (lane == 0) sel[0] = 0;
    __syncthreads();   // one wave: cheap; makes LDS staging visible

    // initial center = point 0 (uniform global load, one time)
    float cx = p[0], cy = p[1], cz = p[2];

    float lmax;
    {
        f32x2 ncx = (f32x2){-cx, -cx}, ncy = (f32x2){-cy, -cy}, ncz = (f32x2){-cz, -cz};
        f32x2 lm2 = (f32x2){-INFINITY, -INFINITY};
#pragma unroll
        for (int r = 0; r < 16; ++r) {
            f32x2 dx = px[r] + ncx, dy = py[r] + ncy, dz = pz[r] + ncz;
            f32x2 a = dx * dx, bb = dy * dy, cc = dz * dz;
            f32x2 s = (a + bb) + cc;
            dist[r] = s;
            lm2 = __builtin_elementwise_max(lm2, s);
        }
        lmax = fmaxf(lm2.x, lm2.y);
    }

    for (int s = 1; s < SQ; ++s) {
        // ---- wave max via DPP ----
        float m = lmax;
        m = maxdpp<0x111>(m);   // row_shr:1
        m = maxdpp<0x112>(m);   // row_shr:2
        m = maxdpp<0x114>(m);   // row_shr:4
        m = maxdpp<0x118>(m);   // row_shr:8
        m = maxdpp<0x142>(m);   // row_bcast:15
        m = maxdpp<0x143>(m);   // row_bcast:31
        float wmax = __builtin_bit_cast(
            float, __builtin_amdgcn_readlane(__builtin_bit_cast(int, m), 63));

        // ---- winning lane: lowest lane whose lane-max == wmax (scalar) ----
        unsigned long long msk = __ballot(lmax == wmax);
        int wl = __ffsll(msk) - 1;

        // ---- per-lane first matching slot: two 16-deep chains + min ----
        int ra = 1000, rb = 1000;
#pragma unroll
        for (int r = 15; r >= 0; --r) {
            ra = (dist[r].x == wmax) ? 2*r     : ra;
            rb = (dist[r].y == wmax) ? 2*r + 1 : rb;
        }
        int ridx = min(ra, rb);
        int rw = __builtin_amdgcn_readlane(ridx, wl);   // wl is uniform
        int gidx = wl * 32 + rw;                        // first-occurrence argmax
        if (lane == 0) sel[s] = gidx;

        // ---- center fetch: one uniform ds_read_b128 ----
        float4 c4 = *reinterpret_cast<const float4*>(&lpos[gidx][0]);
        f32x2 ncx = (f32x2){-c4.x, -c4.x};
        f32x2 ncy = (f32x2){-c4.y, -c4.y};
        f32x2 ncz = (f32x2){-c4.z, -c4.z};

        // ---- packed distance update + fresh lane max ----
        f32x2 lm2 = (f32x2){-INFINITY, -INFINITY};
#pragma unroll
        for (int r = 0; r < 16; ++r) {
            f32x2 dx = px[r] + ncx, dy = py[r] + ncy, dz = pz[r] + ncz;
            f32x2 a = dx * dx, bb = dy * dy, cc = dz * dz;
            f32x2 nd = (a + bb) + cc;
            f32x2 v = __builtin_elementwise_min(dist[r], nd);
            dist[r] = v;
            lm2 = __builtin_elementwise_max(lm2, v);
        }
        lmax = fmaxf(lm2.x, lm2.y);
    }
    __syncthreads();   // sel[] visible for the output pass

    for (int s = lane; s < SQ; s += 64) {
        int id = sel[s];
        idx_out[b*SQ + s] = id;
        q_out[(size_t)(b*SQ + s)*3 + 0] = lpos[id][0];
        q_out[(size_t)(b*SQ + s)*3 + 1] = lpos[id][1];
        q_out[(size_t)(b*SQ + s)*3 + 2] = lpos[id][2];
        batch_out[b*SQ + s] = (float)b;
    }
}

// ---------------------------------------------------------------------------
// Kernel 2: radius ball query, one block per center. Selects the set of the
// K smallest d2 <= R2 (ties -> lower point index), matching lax.top_k's
// stable selection. Order of stored neighbors is irrelevant (max-agg).
// ---------------------------------------------------------------------------
__global__ __launch_bounds__(256)
void ball_kernel(const float* __restrict__ pos, const float* __restrict__ q,
                 int* __restrict__ nbr, int* __restrict__ cnt_out) {
    const int cidx = blockIdx.x;
    const int b = cidx >> 10;
    __shared__ float sd2[CAP];
    __shared__ int   sid[CAP];
    __shared__ int   s_cnt, s_w;
    if (threadIdx.x == 0) { s_cnt = 0; s_w = 0; }
    __syncthreads();

    const float qx = q[(size_t)cidx*3], qy = q[(size_t)cidx*3+1], qz = q[(size_t)cidx*3+2];
    const float* p = pos + (size_t)b * NQ * 3;
    for (int i = threadIdx.x; i < NQ; i += 256) {
        float dx = __fsub_rn(qx, p[3*i]);
        float dy = __fsub_rn(qy, p[3*i+1]);
        float dz = __fsub_rn(qz, p[3*i+2]);
        float d2 = __fadd_rn(__fadd_rn(__fmul_rn(dx, dx), __fmul_rn(dy, dy)),
                             __fmul_rn(dz, dz));
        if (d2 <= R2F) {
            int slot = atomicAdd(&s_cnt, 1);
            if (slot < CAP) { sd2[slot] = d2; sid[slot] = i; }
        }
    }
    __syncthreads();
    int cnt = min(s_cnt, CAP);
    if (cnt <= KQ) {
        for (int t = threadIdx.x; t < cnt; t += 256) nbr[(size_t)cidx*KQ + t] = sid[t];
        if (threadIdx.x == 0) cnt_out[cidx] = cnt;
    } else {
        for (int t = threadIdx.x; t < cnt; t += 256) {
            float d = sd2[t]; int id = sid[t];
            int rank = 0;
            for (int u = 0; u < cnt; ++u) {
                float du = sd2[u];
                rank += (du < d || (du == d && sid[u] < id)) ? 1 : 0;
            }
            if (rank < KQ) { int w = atomicAdd(&s_w, 1); nbr[(size_t)cidx*KQ + w] = id; }
        }
        if (threadIdx.x == 0) cnt_out[cidx] = KQ;
    }
}

// ---------------------------------------------------------------------------
// Kernel 3: xw = x @ w1[:64] + b1  (per-point, hoisted out of the edge loop)
// ---------------------------------------------------------------------------
__global__ __launch_bounds__(128)
void xw_kernel(const float* __restrict__ x, const float* __restrict__ w1,
               const float* __restrict__ b1, float* __restrict__ xw) {
    __shared__ float xs[8][CIN];
    const int r0 = blockIdx.x * 8;
    const int h  = threadIdx.x;
    for (int i = h; i < 8*CIN; i += 128)
        xs[i >> 6][i & 63] = x[(size_t)(r0 + (i >> 6))*CIN + (i & 63)];
    __syncthreads();
    float bb = b1[h];
    float acc[8];
#pragma unroll
    for (int r = 0; r < 8; ++r) acc[r] = bb;
    for (int c = 0; c < CIN; ++c) {
        float wv = w1[c*H1Q + h];
#pragma unroll
        for (int r = 0; r < 8; ++r) acc[r] = fmaf(xs[r][c], wv, acc[r]);
    }
#pragma unroll
    for (int r = 0; r < 8; ++r) xw[(size_t)(r0 + r)*H1Q + h] = acc[r];
}

// ---------------------------------------------------------------------------
// Kernel 4: per-center edge MLP + masked max aggregation.
// ---------------------------------------------------------------------------
__global__ __launch_bounds__(256)
void conv_kernel(const float* __restrict__ pos, const float* __restrict__ q,
                 const int* __restrict__ nbr, const int* __restrict__ cnt_in,
                 const float* __restrict__ xw, const float* __restrict__ w1,
                 const float* __restrict__ w2, const float* __restrict__ b2,
                 float* __restrict__ out) {
    const int cidx = blockIdx.x;
    const int b = cidx >> 10;
    const int tid = threadIdx.x;
    __shared__ float hs[KQ][H1Q];           // 32 KB
    __shared__ float vs[8][COUT];           // 8 KB
    __shared__ float dxs[KQ], dys[KQ], dzs[KQ];
    __shared__ int   js[KQ];

    const int cnt = cnt_in[cidx];
    if (cnt == 0) {
        out[(size_t)cidx*COUT + tid] = 0.0f;
        return;
    }
    const float qx = q[(size_t)cidx*3], qy = q[(size_t)cidx*3+1], qz = q[(size_t)cidx*3+2];
    const float* p = pos + (size_t)b * NQ * 3;
    if (tid < cnt) {
        int j = nbr[(size_t)cidx*KQ + tid];
        js[tid]  = j;
        dxs[tid] = p[3*j]   - qx;
        dys[tid] = p[3*j+1] - qy;
        dzs[tid] = p[3*j+2] - qz;
    }
    __syncthreads();

    const float* w1p = w1 + (size_t)CIN * H1Q;   // rows 64..66
    for (int f = tid; f < cnt*H1Q; f += 256) {
        int e = f >> 7, h = f & 127;
        int j = js[e];
        float v = xw[((size_t)b*NQ + j)*H1Q + h];   // global point row
        v = fmaf(dxs[e], w1p[h],         v);
        v = fmaf(dys[e], w1p[H1Q + h],   v);
        v = fmaf(dzs[e], w1p[2*H1Q + h], v);
        hs[e][h] = fmaxf(v, 0.0f);
    }
    __syncthreads();

    const int grp = tid >> 5;        // 0..7, edge tile
    const int c0  = (tid & 31) * 8;  // 8 contiguous channels
    const int e0  = grp * 8;
    float vmax[8];
#pragma unroll
    for (int j = 0; j < 8; ++j) vmax[j] = -INFINITY;

    const int ne = min(8, cnt - e0);
    if (ne > 0) {
        float acc[8][8];
#pragma unroll
        for (int e = 0; e < 8; ++e)
#pragma unroll
            for (int j = 0; j < 8; ++j) acc[e][j] = 0.0f;

        for (int h = 0; h < H1Q; ++h) {
            const float4 wa = *(const float4*)&w2[(size_t)h*COUT + c0];
            const float4 wb = *(const float4*)&w2[(size_t)h*COUT + c0 + 4];
#pragma unroll
            for (int e = 0; e < 8; ++e) {
                float hv = hs[e0 + e][h];
                acc[e][0] = fmaf(hv, wa.x, acc[e][0]);
                acc[e][1] = fmaf(hv, wa.y, acc[e][1]);
                acc[e][2] = fmaf(hv, wa.z, acc[e][2]);
                acc[e][3] = fmaf(hv, wa.w, acc[e][3]);
                acc[e][4] = fmaf(hv, wb.x, acc[e][4]);
                acc[e][5] = fmaf(hv, wb.y, acc[e][5]);
                acc[e][6] = fmaf(hv, wb.z, acc[e][6]);
                acc[e][7] = fmaf(hv, wb.w, acc[e][7]);
            }
        }
#pragma unroll
        for (int e = 0; e < 8; ++e) {
            if (e < ne) {
#pragma unroll
                for (int j = 0; j < 8; ++j) vmax[j] = fmaxf(vmax[j], acc[e][j]);
            }
        }
    }
#pragma unroll
    for (int j = 0; j < 8; ++j) vs[grp][c0 + j] = vmax[j];
    __syncthreads();

    float m = vs[0][tid];
#pragma unroll
    for (int g = 1; g < 8; ++g) m = fmaxf(m, vs[g][tid]);
    m += b2[tid];
    out[(size_t)cidx*COUT + tid] = m;
}

// ---------------------------------------------------------------------------
extern "C" void kernel_launch(void* const* d_in, const int* in_sizes, int n_in,
                              void* d_out, int out_size, void* d_ws, size_t ws_size,
                              hipStream_t stream) {
    const float* x   = (const float*)d_in[0];
    const float* pos = (const float*)d_in[1];
    // d_in[2] = batch (implicit, unused)
    const float* w1  = (const float*)d_in[3];
    const float* b1  = (const float*)d_in[4];
    const float* w2  = (const float*)d_in[5];
    const float* b2  = (const float*)d_in[6];

    float* out  = (float*)d_out;                         // [B*S, 256]
    float* qbuf = out + (size_t)BQ*SQ*COUT;              // [B*S, 3]
    float* bbuf = qbuf + (size_t)BQ*SQ*3;                // [B*S]

    char* ws = (char*)d_ws;
    int*   idx = (int*)(ws);                                     // 32 KB
    int*   cnt = (int*)(ws + 32768);                             // 32 KB
    int*   nbr = (int*)(ws + 65536);                             // 2 MB
    float* xw  = (float*)(ws + 65536 + (size_t)BQ*SQ*KQ*4);      // 8 MB

    fps_kernel <<<BQ,        64, 0, stream>>>(pos, idx, qbuf, bbuf);
    ball_kernel<<<BQ*SQ,    256, 0, stream>>>(pos, qbuf, nbr, cnt);
    xw_kernel  <<<(BQ*NQ)/8, 128, 0, stream>>>(x, w1, b1, xw);
    conv_kernel<<<BQ*SQ,    256, 0, stream>>>(pos, qbuf, nbr, cnt, xw, w1, w2, b2, out);
}

// Round 5
// 1106.865 us; speedup vs baseline: 1.7828x; 1.0293x over previous
//
#include <hip/hip_runtime.h>
#include <math.h>

#define BQ 8
#define NQ 2048
#define SQ 1024
#define KQ 64
#define CIN 64
#define H1Q 128
#define COUT 256
#define R2F 0.04f     /* f32(0.2**2 in double) = 0x3D23D70A; NOT 0.2f*0.2f */
#define CAP 512
#define XW_ROWS 8     /* rows per xw block (fused path) */

typedef float f32x2 __attribute__((ext_vector_type(2)));

// ---------------------------------------------------------------------------
// DPP wave-max helper (gfx9/CDNA row ops). old = -inf so shifted-in lanes
// contribute the identity. After shr 1,2,4,8 + bcast15 + bcast31, lane 63
// holds the max of all 64 lanes.
// ---------------------------------------------------------------------------
template <int CTRL>
__device__ __forceinline__ float maxdpp(float x) {
    int xi = __builtin_bit_cast(int, x);
    int yi = __builtin_amdgcn_update_dpp((int)0xFF800000, xi, CTRL, 0xF, 0xF, false);
    return fmaxf(x, __builtin_bit_cast(float, yi));
}

// ---------------------------------------------------------------------------
// Fused kernel: blocks 0..7 = FPS (one wave per cloud); blocks 8.. = xw
// (x @ w1[:64] + b1, independent work that fills the otherwise-idle CUs).
//
// FPS: points in registers as float2 pairs (lane-major: lane L owns global
// indices [L*32, L*32+32), reg r holds {L*32+2r, L*32+2r+1}), so
// (lane, reg, elem) lexicographic == global index order and first-occurrence
// argmax is preserved. d2 matches jnp bit-exactly: ((dx*dx+dy*dy)+dz*dz),
// no FMA, no reassoc; x + (-c) is bitwise == x - c.
// Critical-path layout per iteration:
//   update loop -> [own-lmax slot scan || DPP wave-max]  (independent)
//   -> readlane(wmax) -> ballot/ffs (wl) -> readlane(ridx, wl) -> gidx
//   -> one ds_read_b128 of NEGATED center -> update loop.
// ---------------------------------------------------------------------------
__global__ __launch_bounds__(64)
void fps_xw_kernel(const float* __restrict__ pos, int* __restrict__ idx_out,
                   float* __restrict__ q_out, float* __restrict__ batch_out,
                   const float* __restrict__ x, const float* __restrict__ w1,
                   const float* __restrict__ b1, float* __restrict__ xw) {
#pragma clang fp contract(off)
    __shared__ float lnpos[NQ][4];          // NEGATED coords, padded for b128
    __shared__ int   sel[SQ];
    __shared__ float xs[XW_ROWS][CIN];      // xw path scratch

    const int lane = threadIdx.x;

    if (blockIdx.x >= 8) {
        // ---------------- xw path: 8 rows, 64 threads, 2 h-cols/thread ----
        const int r0 = (blockIdx.x - 8) * XW_ROWS;
        for (int i = lane; i < XW_ROWS*CIN; i += 64)
            xs[i >> 6][i & 63] = x[(size_t)(r0 + (i >> 6))*CIN + (i & 63)];
        __syncthreads();
        const int h0 = lane, h1 = lane + 64;
        float acc0[XW_ROWS], acc1[XW_ROWS];
        float bb0 = b1[h0], bb1 = b1[h1];
#pragma unroll
        for (int r = 0; r < XW_ROWS; ++r) { acc0[r] = bb0; acc1[r] = bb1; }
        for (int c = 0; c < CIN; ++c) {
            float w0 = w1[c*H1Q + h0];
            float w2v = w1[c*H1Q + h1];
#pragma unroll
            for (int r = 0; r < XW_ROWS; ++r) {
                float xv = xs[r][c];
                acc0[r] = fmaf(xv, w0,  acc0[r]);
                acc1[r] = fmaf(xv, w2v, acc1[r]);
            }
        }
#pragma unroll
        for (int r = 0; r < XW_ROWS; ++r) {
            xw[(size_t)(r0 + r)*H1Q + h0] = acc0[r];
            xw[(size_t)(r0 + r)*H1Q + h1] = acc1[r];
        }
        return;
    }

    // ---------------- FPS path ----------------
    const int b = blockIdx.x;
    const float* p = pos + (size_t)b * NQ * 3;

    f32x2 px[16], py[16], pz[16], dist[16];
#pragma unroll
    for (int r = 0; r < 16; ++r) {
        int i0 = lane * 32 + 2 * r;
        float x0 = p[3*i0],   y0 = p[3*i0+1], z0 = p[3*i0+2];
        float x1 = p[3*i0+3], y1 = p[3*i0+4], z1 = p[3*i0+5];
        px[r] = (f32x2){x0, x1}; py[r] = (f32x2){y0, y1}; pz[r] = (f32x2){z0, z1};
        lnpos[i0][0]   = -x0; lnpos[i0][1]   = -y0; lnpos[i0][2]   = -z0; lnpos[i0][3]   = 0.f;
        lnpos[i0+1][0] = -x1; lnpos[i0+1][1] = -y1; lnpos[i0+1][2] = -z1; lnpos[i0+1][3] = 0.f;
    }
    if (lane == 0) sel[0] = 0;
    __syncthreads();   // one wave: cheap; makes LDS staging visible

    // initial center = point 0 (uniform global load, one time)
    float cx = p[0], cy = p[1], cz = p[2];

    float lmax;
    {
        f32x2 ncx = (f32x2){-cx, -cx}, ncy = (f32x2){-cy, -cy}, ncz = (f32x2){-cz, -cz};
        f32x2 lm2 = (f32x2){-INFINITY, -INFINITY};
#pragma unroll
        for (int r = 0; r < 16; ++r) {
            f32x2 dx = px[r] + ncx, dy = py[r] + ncy, dz = pz[r] + ncz;
            f32x2 a = dx * dx, bb = dy * dy, cc = dz * dz;
            f32x2 s = (a + bb) + cc;
            dist[r] = s;
            lm2 = __builtin_elementwise_max(lm2, s);
        }
        lmax = fmaxf(lm2.x, lm2.y);
    }

    for (int s = 1; s < SQ; ++s) {
        // ---- per-lane first slot holding own lmax (overlaps DPP below) ----
        int ra = 1000, rb = 1000;
#pragma unroll
        for (int r = 15; r >= 0; --r) {
            ra = (dist[r].x == lmax) ? 2*r     : ra;
            rb = (dist[r].y == lmax) ? 2*r + 1 : rb;
        }
        int ridx = min(ra, rb);

        // ---- wave max via DPP (independent of the scan above) ----
        float m = lmax;
        m = maxdpp<0x111>(m);   // row_shr:1
        m = maxdpp<0x112>(m);   // row_shr:2
        m = maxdpp<0x114>(m);   // row_shr:4
        m = maxdpp<0x118>(m);   // row_shr:8
        m = maxdpp<0x142>(m);   // row_bcast:15
        m = maxdpp<0x143>(m);   // row_bcast:31
        float wmax = __builtin_bit_cast(
            float, __builtin_amdgcn_readlane(__builtin_bit_cast(int, m), 63));

        // ---- winning lane = lowest lane whose lane-max == wmax ----
        unsigned long long msk = __ballot(lmax == wmax);
        int wl = __ffsll(msk) - 1;
        int rw = __builtin_amdgcn_readlane(ridx, wl);   // wl is uniform
        int gidx = wl * 32 + rw;                        // first-occurrence argmax
        if (lane == 0) sel[s] = gidx;

        // ---- center fetch: one uniform ds_read_b128 of NEGATED coords ----
        float4 nc4 = *reinterpret_cast<const float4*>(&lnpos[gidx][0]);
        f32x2 ncx = (f32x2){nc4.x, nc4.x};
        f32x2 ncy = (f32x2){nc4.y, nc4.y};
        f32x2 ncz = (f32x2){nc4.z, nc4.z};

        // ---- packed distance update + fresh lane max ----
        f32x2 lm2 = (f32x2){-INFINITY, -INFINITY};
#pragma unroll
        for (int r = 0; r < 16; ++r) {
            f32x2 dx = px[r] + ncx, dy = py[r] + ncy, dz = pz[r] + ncz;
            f32x2 a = dx * dx, bb = dy * dy, cc = dz * dz;
            f32x2 nd = (a + bb) + cc;
            f32x2 v = __builtin_elementwise_min(dist[r], nd);
            dist[r] = v;
            lm2 = __builtin_elementwise_max(lm2, v);
        }
        lmax = fmaxf(lm2.x, lm2.y);
    }
    __syncthreads();   // sel[] visible for the output pass

    for (int s = lane; s < SQ; s += 64) {
        int id = sel[s];
        idx_out[b*SQ + s] = id;
        q_out[(size_t)(b*SQ + s)*3 + 0] = -lnpos[id][0];   // -(-x): bit-exact
        q_out[(size_t)(b*SQ + s)*3 + 1] = -lnpos[id][1];
        q_out[(size_t)(b*SQ + s)*3 + 2] = -lnpos[id][2];
        batch_out[b*SQ + s] = (float)b;
    }
}

// ---------------------------------------------------------------------------
// Kernel 2: radius ball query, one block per center. Selects the set of the
// K smallest d2 <= R2 (ties -> lower point index), matching lax.top_k's
// stable selection. Order of stored neighbors is irrelevant (max-agg).
// ---------------------------------------------------------------------------
__global__ __launch_bounds__(256)
void ball_kernel(const float* __restrict__ pos, const float* __restrict__ q,
                 int* __restrict__ nbr, int* __restrict__ cnt_out) {
    const int cidx = blockIdx.x;
    const int b = cidx >> 10;
    __shared__ float sd2[CAP];
    __shared__ int   sid[CAP];
    __shared__ int   s_cnt, s_w;
    if (threadIdx.x == 0) { s_cnt = 0; s_w = 0; }
    __syncthreads();

    const float qx = q[(size_t)cidx*3], qy = q[(size_t)cidx*3+1], qz = q[(size_t)cidx*3+2];
    const float* p = pos + (size_t)b * NQ * 3;
    for (int i = threadIdx.x; i < NQ; i += 256) {
        float dx = __fsub_rn(qx, p[3*i]);
        float dy = __fsub_rn(qy, p[3*i+1]);
        float dz = __fsub_rn(qz, p[3*i+2]);
        float d2 = __fadd_rn(__fadd_rn(__fmul_rn(dx, dx), __fmul_rn(dy, dy)),
                             __fmul_rn(dz, dz));
        if (d2 <= R2F) {
            int slot = atomicAdd(&s_cnt, 1);
            if (slot < CAP) { sd2[slot] = d2; sid[slot] = i; }
        }
    }
    __syncthreads();
    int cnt = min(s_cnt, CAP);
    if (cnt <= KQ) {
        for (int t = threadIdx.x; t < cnt; t += 256) nbr[(size_t)cidx*KQ + t] = sid[t];
        if (threadIdx.x == 0) cnt_out[cidx] = cnt;
    } else {
        for (int t = threadIdx.x; t < cnt; t += 256) {
            float d = sd2[t]; int id = sid[t];
            int rank = 0;
            for (int u = 0; u < cnt; ++u) {
                float du = sd2[u];
                rank += (du < d || (du == d && sid[u] < id)) ? 1 : 0;
            }
            if (rank < KQ) { int w = atomicAdd(&s_w, 1); nbr[(size_t)cidx*KQ + w] = id; }
        }
        if (threadIdx.x == 0) cnt_out[cidx] = KQ;
    }
}

// ---------------------------------------------------------------------------
// Kernel 4: per-center edge MLP + masked max aggregation.
// ---------------------------------------------------------------------------
__global__ __launch_bounds__(256)
void conv_kernel(const float* __restrict__ pos, const float* __restrict__ q,
                 const int* __restrict__ nbr, const int* __restrict__ cnt_in,
                 const float* __restrict__ xw, const float* __restrict__ w1,
                 const float* __restrict__ w2, const float* __restrict__ b2,
                 float* __restrict__ out) {
    const int cidx = blockIdx.x;
    const int b = cidx >> 10;
    const int tid = threadIdx.x;
    __shared__ float hs[KQ][H1Q];           // 32 KB
    __shared__ float vs[8][COUT];           // 8 KB
    __shared__ float dxs[KQ], dys[KQ], dzs[KQ];
    __shared__ int   js[KQ];

    const int cnt = cnt_in[cidx];
    if (cnt == 0) {
        out[(size_t)cidx*COUT + tid] = 0.0f;
        return;
    }
    const float qx = q[(size_t)cidx*3], qy = q[(size_t)cidx*3+1], qz = q[(size_t)cidx*3+2];
    const float* p = pos + (size_t)b * NQ * 3;
    if (tid < cnt) {
        int j = nbr[(size_t)cidx*KQ + tid];
        js[tid]  = j;
        dxs[tid] = p[3*j]   - qx;
        dys[tid] = p[3*j+1] - qy;
        dzs[tid] = p[3*j+2] - qz;
    }
    __syncthreads();

    const float* w1p = w1 + (size_t)CIN * H1Q;   // rows 64..66
    for (int f = tid; f < cnt*H1Q; f += 256) {
        int e = f >> 7, h = f & 127;
        int j = js[e];
        float v = xw[((size_t)b*NQ + j)*H1Q + h];   // global point row
        v = fmaf(dxs[e], w1p[h],         v);
        v = fmaf(dys[e], w1p[H1Q + h],   v);
        v = fmaf(dzs[e], w1p[2*H1Q + h], v);
        hs[e][h] = fmaxf(v, 0.0f);
    }
    __syncthreads();

    const int grp = tid >> 5;        // 0..7, edge tile
    const int c0  = (tid & 31) * 8;  // 8 contiguous channels
    const int e0  = grp * 8;
    float vmax[8];
#pragma unroll
    for (int j = 0; j < 8; ++j) vmax[j] = -INFINITY;

    const int ne = min(8, cnt - e0);
    if (ne > 0) {
        float acc[8][8];
#pragma unroll
        for (int e = 0; e < 8; ++e)
#pragma unroll
            for (int j = 0; j < 8; ++j) acc[e][j] = 0.0f;

        for (int h = 0; h < H1Q; ++h) {
            const float4 wa = *(const float4*)&w2[(size_t)h*COUT + c0];
            const float4 wb = *(const float4*)&w2[(size_t)h*COUT + c0 + 4];
#pragma unroll
            for (int e = 0; e < 8; ++e) {
                float hv = hs[e0 + e][h];
                acc[e][0] = fmaf(hv, wa.x, acc[e][0]);
                acc[e][1] = fmaf(hv, wa.y, acc[e][1]);
                acc[e][2] = fmaf(hv, wa.z, acc[e][2]);
                acc[e][3] = fmaf(hv, wa.w, acc[e][3]);
                acc[e][4] = fmaf(hv, wb.x, acc[e][4]);
                acc[e][5] = fmaf(hv, wb.y, acc[e][5]);
                acc[e][6] = fmaf(hv, wb.z, acc[e][6]);
                acc[e][7] = fmaf(hv, wb.w, acc[e][7]);
            }
        }
#pragma unroll
        for (int e = 0; e < 8; ++e) {
            if (e < ne) {
#pragma unroll
                for (int j = 0; j < 8; ++j) vmax[j] = fmaxf(vmax[j], acc[e][j]);
            }
        }
    }
#pragma unroll
    for (int j = 0; j < 8; ++j) vs[grp][c0 + j] = vmax[j];
    __syncthreads();

    float m = vs[0][tid];
#pragma unroll
    for (int g = 1; g < 8; ++g) m = fmaxf(m, vs[g][tid]);
    m += b2[tid];
    out[(size_t)cidx*COUT + tid] = m;
}

// ---------------------------------------------------------------------------
extern "C" void kernel_launch(void* const* d_in, const int* in_sizes, int n_in,
                              void* d_out, int out_size, void* d_ws, size_t ws_size,
                              hipStream_t stream) {
    const float* x   = (const float*)d_in[0];
    const float* pos = (const float*)d_in[1];
    // d_in[2] = batch (implicit, unused)
    const float* w1  = (const float*)d_in[3];
    const float* b1  = (const float*)d_in[4];
    const float* w2  = (const float*)d_in[5];
    const float* b2  = (const float*)d_in[6];

    float* out  = (float*)d_out;                         // [B*S, 256]
    float* qbuf = out + (size_t)BQ*SQ*COUT;              // [B*S, 3]
    float* bbuf = qbuf + (size_t)BQ*SQ*3;                // [B*S]

    char* ws = (char*)d_ws;
    int*   idx = (int*)(ws);                                     // 32 KB
    int*   cnt = (int*)(ws + 32768);                             // 32 KB
    int*   nbr = (int*)(ws + 65536);                             // 2 MB
    float* xw  = (float*)(ws + 65536 + (size_t)BQ*SQ*KQ*4);      // 8 MB

    const int xw_blocks = (BQ * NQ) / XW_ROWS;   // 2048
    fps_xw_kernel<<<8 + xw_blocks, 64, 0, stream>>>(pos, idx, qbuf, bbuf,
                                                    x, w1, b1, xw);
    ball_kernel  <<<BQ*SQ, 256, 0, stream>>>(pos, qbuf, nbr, cnt);
    conv_kernel  <<<BQ*SQ, 256, 0, stream>>>(pos, qbuf, nbr, cnt, xw, w1, w2, b2, out);
}